// Round 10
// baseline (156.035 us; speedup 1.0000x reference)
//
#include <hip/hip_runtime.h>
#include <stdint.h>

#define NCAT  919
#define KDIM  400
#define NDIM  100
#define BK    32
#define NSTEP 13                 // ceil(400/32); step 12 has 16 valid k
#define KPAD  408                // bf16; row = 816 B (16B-aligned b128; read banks 2-way free)
#define NROWS 100                // n=6 fragment row-clamps; cols 100..111 never stored
                                 // LDS = 100*408*2 = 81600 B

typedef float  f32x4  __attribute__((ext_vector_type(4)));
typedef __bf16 bf16x8 __attribute__((ext_vector_type(8)));
typedef __bf16 bf16x2 __attribute__((ext_vector_type(2)));

__global__ void __launch_bounds__(512, 2)
cat_dense(const float* __restrict__ in, const float* __restrict__ wt,
          const float* __restrict__ bias, float* __restrict__ out)
{
  __shared__ __bf16 wlds[NROWS * KPAD];

  // Bijective XCD-aware swizzle (m204): 919 = 7*115 + 114. Consecutive categories
  // share an XCD L2 -> partial 128B output lines merge before writeback.
  const int ob   = blockIdx.x;
  const int xcd  = ob & 7;
  const int bidx = ob >> 3;
  const int c    = (xcd < 7 ? xcd * 115 : 805 + (xcd - 7) * 114) + bidx;

  const int tid  = threadIdx.x;
  const int lane = tid & 63;
  const int wave = tid >> 6;
  const int rl   = lane & 15;                // fragment row (A) / col (B/D)
  const int kg   = (lane >> 4) * 8;          // fragment k offset

  const size_t rstride = (size_t)NCAT * KDIM;
  const float* gA0 = in + (size_t)c * KDIM + (size_t)(wave * 32 + rl) * rstride;
  const float* gA1 = gA0 + (size_t)16 * rstride;
  const float* gW  = wt + (size_t)c * (KDIM * NDIM);

  // 6 A-prefetch slots (96 VGPR). Schedule: prologue A(0..3); bursts at
  // t=0,2,4 (A(t+4),A(t+5)); singles at t=7 (A10,A11) and t=9 (A12) placed
  // AFTER barrier-2 so no __syncthreads ever drains a just-issued load.
  // Slot (T)%6 is always free >=2 steps before reuse (consumed at T-6).
  f32x4 areg[6][2][2];

#define LOADA(T) do {                                                      \
    const int kb_ = (T) * BK + kg;                                         \
    if (kb_ + 8 <= KDIM) {   /* per-lane K-tail mask (step 12, kg>=16) */  \
      areg[(T) % 6][0][0] = *(const f32x4*)(gA0 + kb_);                    \
      areg[(T) % 6][0][1] = *(const f32x4*)(gA0 + kb_ + 4);                \
      areg[(T) % 6][1][0] = *(const f32x4*)(gA1 + kb_);                    \
      areg[(T) % 6][1][1] = *(const f32x4*)(gA1 + kb_ + 4);                \
    } else {                                                               \
      areg[(T) % 6][0][0] = f32x4{0,0,0,0};                                \
      areg[(T) % 6][0][1] = f32x4{0,0,0,0};                                \
      areg[(T) % 6][1][0] = f32x4{0,0,0,0};                                \
      areg[(T) % 6][1][1] = f32x4{0,0,0,0};                                \
    }                                                                      \
  } while (0)

  // ---- prologue: 4 A-steps in flight; they land during W staging ----
  LOADA(0); LOADA(1); LOADA(2); LOADA(3);

  // ---- W stage, half 1: k < 224 (kp < 112), kp-SWEEP mapping ----
  // pc = nq*112 + kp: consecutive lanes -> consecutive kp -> consecutive LDS
  // dwords -> conflict-free ds_writes (r9 nq-sweep was ~16-way conflicted).
  // Global reads become 800B-strided 16B requests; W_c (160KB) << L2, every
  // line fetched from HBM once, re-requests are L2 hits -> HBM traffic same.
  f32x4 wa0[6], wa1[6];
  #pragma unroll
  for (int i = 0; i < 6; ++i) {
    const int pc = tid + i * 512;
    if (pc < 2800) {
      const int nq = pc / 112;
      const int kp = pc - nq * 112;
      const float* p = gW + (size_t)(2 * kp) * NDIM + nq * 4;
      wa0[i] = *(const f32x4*)p;
      wa1[i] = *(const f32x4*)(p + NDIM);
    }
  }
  #pragma unroll
  for (int i = 0; i < 6; ++i) {
    const int pc = tid + i * 512;
    if (pc < 2800) {
      const int nq = pc / 112;
      const int kp = pc - nq * 112;
      #pragma unroll
      for (int j = 0; j < 4; ++j) {
        bf16x2 pk = { (__bf16)wa0[i][j], (__bf16)wa1[i][j] };
        *(bf16x2*)&wlds[(nq * 4 + j) * KPAD + 2 * kp] = pk;
      }
    }
  }
  // Barrier 1: k<224 visible to all. Full __syncthreads(): real fence
  // semantics (round-4 lesson). A(0..3) drained here — they've long arrived.
  __syncthreads();

  // ---- W stage, half 2: ISSUE loads now; they land under compute t=0..6 ----
  f32x4 wb0[5], wb1[5];
  #pragma unroll
  for (int i = 0; i < 5; ++i) {
    const int pc = tid + i * 512;
    if (pc < 2200) {
      const int nq = pc / 88;
      const int kp = 112 + (pc - nq * 88);
      const float* p = gW + (size_t)(2 * kp) * NDIM + nq * 4;
      wb0[i] = *(const f32x4*)p;
      wb1[i] = *(const f32x4*)(p + NDIM);
    }
  }
  // Pin program order: do NOT let the scheduler sink these loads down to
  // their t==6 use (round-7 failure mode under register pressure).
  __builtin_amdgcn_sched_barrier(0);

  f32x4 acc[2][7];
  #pragma unroll
  for (int m = 0; m < 2; ++m)
    #pragma unroll
    for (int n = 0; n < 7; ++n) acc[m][n] = f32x4{0, 0, 0, 0};

  // ---- main loop: t=0..6 read k<224; write half-2 + barrier; t=7..12 ----
  #pragma unroll
  for (int t = 0; t < NSTEP; ++t) {
    const int pp = t % 6;
    bf16x8 a0, a1;
    #pragma unroll
    for (int j = 0; j < 4; ++j) {            // vmcnt wait for A(t) lands here
      a0[j]     = (__bf16)areg[pp][0][0][j];
      a0[4 + j] = (__bf16)areg[pp][0][1][j];
      a1[j]     = (__bf16)areg[pp][1][0][j];
      a1[4 + j] = (__bf16)areg[pp][1][1][j];
    }
    // A-prefetch schedule (see areg comment). 256B-per-row page bursts.
    if (t == 0 || t == 2 || t == 4) { LOADA(t + 4); LOADA(t + 5); }
    if (t == 7)                     { LOADA(10);    LOADA(11);    }
    if (t == 9)                     { LOADA(12);                  }

    // K-clamp: lanes that clamp (t=12, kg>=16) have A==0 -> finite B suffices.
    const int kb2  = t * BK + kg;
    const int koff = (kb2 <= KDIM - 8) ? kb2 : (KDIM - 8);
    #pragma unroll
    for (int n = 0; n < 7; ++n) {
      // n=6 row-clamp: cols 96..99 (rl<4) get true rows; cols>=100 never
      // stored; clamped lanes read identical addresses -> LDS broadcast.
      const int brow = n * 16 + (n == 6 ? (rl & 3) : rl);
      bf16x8 b = *(const bf16x8*)&wlds[brow * KPAD + koff];
      acc[0][n] = __builtin_amdgcn_mfma_f32_16x16x32_bf16(a0, b, acc[0][n], 0, 0, 0);
      acc[1][n] = __builtin_amdgcn_mfma_f32_16x16x32_bf16(a1, b, acc[1][n], 0, 0, 0);
    }

    if (t == 6) {
      // Half-2 loads arrived during t=0..6; conflict-free ds_writes, then
      // barrier 2. In-flight A here = A(8),A(9) (issued t=4) — arrived, so
      // the vmcnt(0) drain is ~free.
      #pragma unroll
      for (int i = 0; i < 5; ++i) {
        const int pc = tid + i * 512;
        if (pc < 2200) {
          const int nq = pc / 88;
          const int kp = 112 + (pc - nq * 88);
          #pragma unroll
          for (int j = 0; j < 4; ++j) {
            bf16x2 pk = { (__bf16)wb0[i][j], (__bf16)wb1[i][j] };
            *(bf16x2*)&wlds[(nq * 4 + j) * KPAD + 2 * kp] = pk;
          }
        }
      }
      __syncthreads();
    }
  }

  // ---- epilogue: C/D map (16x16 family): col = lane&15, row = (lane>>4)*4 + reg ----
  const float* gB = bias + (size_t)c * NDIM;
  float* gO = out + (size_t)c * NDIM;
  #pragma unroll
  for (int n = 0; n < 7; ++n) {
    const int col = n * 16 + rl;
    if (col < NDIM) {
      const float bv = gB[col];
      #pragma unroll
      for (int m = 0; m < 2; ++m) {
        const int r0 = wave * 32 + m * 16 + (lane >> 4) * 4;
        #pragma unroll
        for (int j = 0; j < 4; ++j) {
          gO[(size_t)(r0 + j) * ((size_t)NCAT * NDIM) + col] = acc[m][n][j] + bv;
        }
      }
    }
  }
}

extern "C" void kernel_launch(void* const* d_in, const int* in_sizes, int n_in,
                              void* d_out, int out_size, void* d_ws, size_t ws_size,
                              hipStream_t stream) {
  const float* in   = (const float*)d_in[0];
  const float* wt   = (const float*)d_in[1];
  const float* bias = (const float*)d_in[2];
  float* o          = (float*)d_out;
  cat_dense<<<dim3(NCAT), dim3(512), 0, stream>>>(in, wt, bias, o);
}

// Round 11
// 144.350 us; speedup vs baseline: 1.0810x; 1.0810x over previous
//
#include <hip/hip_runtime.h>
#include <stdint.h>

#define NCAT  919
#define KDIM  400
#define NDIM  100
#define BK    32
#define NSTEP 13                 // ceil(400/32); step 12 has 16 valid k
#define KPAD  408                // bf16; row = 816 B (16B-aligned b128; read banks 2-way free)
#define NROWS 100                // n=6 fragment row-clamps; cols 100..111 never stored
                                 // LDS = 100*408*2 = 81600 B

typedef float  f32x4  __attribute__((ext_vector_type(4)));
typedef __bf16 bf16x8 __attribute__((ext_vector_type(8)));
typedef __bf16 bf16x2 __attribute__((ext_vector_type(2)));

__global__ void __launch_bounds__(512, 2)
cat_dense(const float* __restrict__ in, const float* __restrict__ wt,
          const float* __restrict__ bias, float* __restrict__ out)
{
  __shared__ __bf16 wlds[NROWS * KPAD];

  // Bijective XCD-aware swizzle (m204): 919 = 7*115 + 114. Consecutive categories
  // share an XCD L2 -> partial 128B output lines merge before writeback.
  const int ob   = blockIdx.x;
  const int xcd  = ob & 7;
  const int bidx = ob >> 3;
  const int c    = (xcd < 7 ? xcd * 115 : 805 + (xcd - 7) * 114) + bidx;

  const int tid  = threadIdx.x;
  const int lane = tid & 63;
  const int wave = tid >> 6;
  const int rl   = lane & 15;                // fragment row (A) / col (B/D)
  const int kg   = (lane >> 4) * 8;          // fragment k offset

  const size_t rstride = (size_t)NCAT * KDIM;
  const float* gA0 = in + (size_t)c * KDIM + (size_t)(wave * 32 + rl) * rstride;
  const float* gA1 = gA0 + (size_t)16 * rstride;
  const float* gW  = wt + (size_t)c * (KDIM * NDIM);

  // 6 A-prefetch slots (96 VGPR). Bursts of two steps (256B/row page runs,
  // r9-proven) at t=0,2,4; singles at t=8 (A10,A11: AFTER barrier-2) and t=9.
  // Slot T%6: always consumed >=2 steps before rewrite (verified schedule).
  f32x4 areg[6][2][2];

#define LOADA(T) do {                                                      \
    const int kb_ = (T) * BK + kg;                                         \
    if (kb_ + 8 <= KDIM) {   /* per-lane K-tail mask (step 12, kg>=16) */  \
      areg[(T) % 6][0][0] = *(const f32x4*)(gA0 + kb_);                    \
      areg[(T) % 6][0][1] = *(const f32x4*)(gA0 + kb_ + 4);                \
      areg[(T) % 6][1][0] = *(const f32x4*)(gA1 + kb_);                    \
      areg[(T) % 6][1][1] = *(const f32x4*)(gA1 + kb_ + 4);                \
    } else {                                                               \
      areg[(T) % 6][0][0] = f32x4{0,0,0,0};                                \
      areg[(T) % 6][0][1] = f32x4{0,0,0,0};                                \
      areg[(T) % 6][1][0] = f32x4{0,0,0,0};                                \
      areg[(T) % 6][1][1] = f32x4{0,0,0,0};                                \
    }                                                                      \
  } while (0)

  // ---- prologue: 4 A-steps + bias in flight; they land during W staging ----
  LOADA(0); LOADA(1); LOADA(2); LOADA(3);

  // Bias hoisted: kills the epilogue load->add->store latency chain.
  const float* gB = bias + (size_t)c * NDIM;
  float bv[7];
  #pragma unroll
  for (int n = 0; n < 7; ++n) {
    const int col = n * 16 + rl;
    bv[n] = (col < NDIM) ? gB[col] : 0.f;
  }

  // ---- W stage half 1: kp < 128 (k < 256), nq-SWEEP mapping (r9-proven:
  // consecutive lanes sweep nq -> 400B coalesced global runs). Load-all-
  // then-write-all so the HBM round-trips overlap instead of chaining.
  f32x4 wa0[7], wa1[7];
  #pragma unroll
  for (int i = 0; i < 7; ++i) {
    const int pc = tid + i * 512;              // pc = kp*25 + nq, kp<128
    if (pc < 3200) {
      const int kp = pc / 25;
      const int nq = pc - kp * 25;
      const float* p = gW + (size_t)(2 * kp) * NDIM + nq * 4;
      wa0[i] = *(const f32x4*)p;
      wa1[i] = *(const f32x4*)(p + NDIM);
    }
  }
  #pragma unroll
  for (int i = 0; i < 7; ++i) {
    const int pc = tid + i * 512;
    if (pc < 3200) {
      const int kp = pc / 25;
      const int nq = pc - kp * 25;
      #pragma unroll
      for (int j = 0; j < 4; ++j) {
        bf16x2 pk = { (__bf16)wa0[i][j], (__bf16)wa1[i][j] };
        *(bf16x2*)&wlds[(nq * 4 + j) * KPAD + 2 * kp] = pk;
      }
    }
  }
  // Barrier 1: k<256 visible. __syncthreads = real fence (round-4 lesson).
  __syncthreads();

  // ---- W stage half 2: kp in [128,200) (k in [256,400)). ISSUE loads now;
  // they land under compute t=0..7. Only 8 f32x4 (32 VGPR) held live.
  f32x4 wb0[4], wb1[4];
  #pragma unroll
  for (int i = 0; i < 4; ++i) {
    const int pc = tid + i * 512;              // pc = (kp-128)*25 + nq
    if (pc < 1800) {
      const int kp = 128 + pc / 25;
      const int nq = pc - (kp - 128) * 25;
      const float* p = gW + (size_t)(2 * kp) * NDIM + nq * 4;
      wb0[i] = *(const f32x4*)p;
      wb1[i] = *(const f32x4*)(p + NDIM);
    }
  }
  // Pin program order: don't let the scheduler sink these to their t==7 use
  // (round-7 failure mode under register pressure).
  __builtin_amdgcn_sched_barrier(0);

  f32x4 acc[2][7];
  #pragma unroll
  for (int m = 0; m < 2; ++m)
    #pragma unroll
    for (int n = 0; n < 7; ++n) acc[m][n] = f32x4{0, 0, 0, 0};

  // ---- main loop: t=0..7 read k<256; write half-2 + barrier at end of t=7;
  // t=8..12 read k>=256. ----
  #pragma unroll
  for (int t = 0; t < NSTEP; ++t) {
    const int pp = t % 6;
    bf16x8 a0, a1;
    #pragma unroll
    for (int j = 0; j < 4; ++j) {              // vmcnt wait for A(t) lands here
      a0[j]     = (__bf16)areg[pp][0][0][j];
      a0[4 + j] = (__bf16)areg[pp][0][1][j];
      a1[j]     = (__bf16)areg[pp][1][0][j];
      a1[4 + j] = (__bf16)areg[pp][1][1][j];
    }
    // A-prefetch: 256B page bursts; t=8 issues come AFTER barrier-2 so the
    // mid-loop __syncthreads never drains a just-issued load (in-flight there:
    // A8,A9 issued at t=4 — long arrived).
    if (t == 0 || t == 2 || t == 4) { LOADA(t + 4); LOADA(t + 5); }
    if (t == 8)                     { LOADA(10);    LOADA(11);    }
    if (t == 9)                     { LOADA(12);                  }

    // K-clamp: lanes that clamp (t=12, kg>=16) have A==0 -> finite B suffices.
    const int kb2  = t * BK + kg;
    const int koff = (kb2 <= KDIM - 8) ? kb2 : (KDIM - 8);
    #pragma unroll
    for (int n = 0; n < 7; ++n) {
      // n=6 row-clamp: cols 96..99 (rl<4) get true rows; cols>=100 never
      // stored; clamped lanes read identical addresses -> LDS broadcast.
      const int brow = n * 16 + (n == 6 ? (rl & 3) : rl);
      bf16x8 b = *(const bf16x8*)&wlds[brow * KPAD + koff];
      acc[0][n] = __builtin_amdgcn_mfma_f32_16x16x32_bf16(a0, b, acc[0][n], 0, 0, 0);
      acc[1][n] = __builtin_amdgcn_mfma_f32_16x16x32_bf16(a1, b, acc[1][n], 0, 0, 0);
    }

    if (t == 7) {
      // Half-2 loads arrived during t=0..7; write + barrier 2.
      #pragma unroll
      for (int i = 0; i < 4; ++i) {
        const int pc = tid + i * 512;
        if (pc < 1800) {
          const int kp = 128 + pc / 25;
          const int nq = pc - (kp - 128) * 25;
          #pragma unroll
          for (int j = 0; j < 4; ++j) {
            bf16x2 pk = { (__bf16)wb0[i][j], (__bf16)wb1[i][j] };
            *(bf16x2*)&wlds[(nq * 4 + j) * KPAD + 2 * kp] = pk;
          }
        }
      }
      __syncthreads();
    }
  }

  // ---- epilogue: C/D map (16x16 family): col = lane&15, row = (lane>>4)*4 + reg ----
  float* gO = out + (size_t)c * NDIM;
  #pragma unroll
  for (int n = 0; n < 7; ++n) {
    const int col = n * 16 + rl;
    if (col < NDIM) {
      #pragma unroll
      for (int m = 0; m < 2; ++m) {
        const int r0 = wave * 32 + m * 16 + (lane >> 4) * 4;
        #pragma unroll
        for (int j = 0; j < 4; ++j) {
          gO[(size_t)(r0 + j) * ((size_t)NCAT * NDIM) + col] = acc[m][n][j] + bv[n];
        }
      }
    }
  }
}

extern "C" void kernel_launch(void* const* d_in, const int* in_sizes, int n_in,
                              void* d_out, int out_size, void* d_ws, size_t ws_size,
                              hipStream_t stream) {
  const float* in   = (const float*)d_in[0];
  const float* wt   = (const float*)d_in[1];
  const float* bias = (const float*)d_in[2];
  float* o          = (float*)d_out;
  cat_dense<<<dim3(NCAT), dim3(512), 0, stream>>>(in, wt, bias, o);
}